// Round 20
// baseline (109.615 us; speedup 1.0000x reference)
//
#include <hip/hip_runtime.h>
#include <math.h>

#define B_SZ 16384
#define D_DIM 128
#define A_SZ 8192
#define K_SZ 64
#define L2_REG_F 0.25f
#define CONV_BLK 2048  // convert blocks (x4 waves -> 2 rows/wave)
#define NBLK 2048      // fused blocks: 4 waves/block, 1 wave per anchor
#define F32BLK 4096    // fp32 fallback blocks (R6-validated geometry)
#define NPART (CONV_BLK + NBLK)

typedef float vfloat2 __attribute__((ext_vector_type(2)));

__device__ __forceinline__ float wave_reduce_sum(float v) {
    #pragma unroll
    for (int off = 32; off > 0; off >>= 1)
        v += __shfl_xor(v, off, 64);
    return v;
}

__device__ __forceinline__ float wave_reduce_max(float v) {
    #pragma unroll
    for (int off = 32; off > 0; off >>= 1)
        v = fmaxf(v, __shfl_xor(v, off, 64));
    return v;
}

__device__ __forceinline__ float dot4(float4 a, float4 b) {
    return a.x * b.x + a.y * b.y + a.z * b.z + a.w * b.w;
}

// Pre-pass (R12/R19-measured, absmax 0.0): fp32 -> fp8 e4m3 table fused with
// the exact-fp32 L2-norm sum. NT stores (R19: neutral, kept).
__global__ __launch_bounds__(256) void convert_kernel(const float* __restrict__ embed,
                                                      unsigned short* __restrict__ tab,
                                                      float* __restrict__ partial) {
    __shared__ float red[4];
    const int wave = threadIdx.x >> 6;
    const int lane = threadIdx.x & 63;
    const int gw   = blockIdx.x * 4 + wave;           // 0..8191
    float acc = 0.f;
    #pragma unroll
    for (int r = 0; r < 2; ++r) {                     // 2 contiguous rows/wave
        const int row = gw * 2 + r;
        const float2* rr = (const float2*)(embed + (size_t)row * D_DIM);
        float2 v = rr[lane];                          // elems 2*lane, 2*lane+1
        acc += sqrtf(wave_reduce_sum(v.x * v.x + v.y * v.y));  // exact fp32 norm
        // HW RNE fp32->fp8 e4m3 (OCP on gfx950), 2 elems packed in low ushort
        unsigned pk = (unsigned)__builtin_amdgcn_cvt_pk_fp8_f32(v.x, v.y, 0, false);
        __builtin_nontemporal_store((unsigned short)pk,
                                    &tab[(size_t)row * 64 + lane]);
    }
    if (lane == 0) red[wave] = acc * (L2_REG_F / (float)B_SZ); // pre-scaled
    __syncthreads();
    if (threadIdx.x == 0)
        partial[blockIdx.x] = red[0] + red[1] + red[2] + red[3];
}

// Main (R12-validated, absmax 0.0). DECOMPOSITION PROBE THIS ROUND: this
// kernel is launched 4x back-to-back (idempotent: pure recompute + same
// plain stores). fused_dur = (total - 81.3)/3.
__global__ __launch_bounds__(256) void fused_kernel(const float* __restrict__ embed,
                                                    const unsigned short* __restrict__ tab,
                                                    const int* __restrict__ anc_ind,
                                                    const int* __restrict__ pos_ind,
                                                    const int* __restrict__ neg_ind,
                                                    float* __restrict__ partial) {
    __shared__ float red[4];
    const int wave = threadIdx.x >> 6;
    const int lane = threadIdx.x & 63;
    const int i    = blockIdx.x * 4 + wave;          // anchor id 0..8191
    const int g    = lane >> 3;                      // group: rows g*8..g*8+7
    const int c    = lane & 7;                       // 16B chunk in the row

    // ---- this group's 8 row ids (contiguous, no lane shuffle needed) ----
    const int4* nbp = (const int4*)(neg_ind + (size_t)i * K_SZ + g * 8);
    int4 nlo = nbp[0], nhi = nbp[1];

    // ---- a/p chunks: lane covers elems c*16..c*16+15 (4 float4s) ----
    const int ai = anc_ind[i];                       // wave-uniform
    const int pi = pos_ind[i];
    const float4* a4 = (const float4*)(embed + (size_t)ai * D_DIM);
    const float4* p4 = (const float4*)(embed + (size_t)pi * D_DIM);
    float4 A0 = a4[c * 4 + 0], A1 = a4[c * 4 + 1];
    float4 A2 = a4[c * 4 + 2], A3 = a4[c * 4 + 3];
    float4 P0 = p4[c * 4 + 0], P1 = p4[c * 4 + 1];
    float4 P2 = p4[c * 4 + 2], P3 = p4[c * 4 + 3];

    // ---- 8 gathers: one full 128B fp8 line per row, all in flight ----
    int nidx[8] = {nlo.x, nlo.y, nlo.z, nlo.w, nhi.x, nhi.y, nhi.z, nhi.w};
    uint4 q[8];
    #pragma unroll
    for (int p = 0; p < 8; ++p)
        q[p] = ((const uint4*)(tab + (size_t)nidx[p] * 64))[c];

    // ---- a.p (exact): lane's 16-elem partial, 3-shfl group reduce ----
    float app = dot4(A0, P0) + dot4(A1, P1) + dot4(A2, P2) + dot4(A3, P3);
    app += __shfl_xor(app, 1, 64);
    app += __shfl_xor(app, 2, 64);
    app += __shfl_xor(app, 4, 64);

    // packed-fp32 A pairs for the fp8 dot chain
    vfloat2 Av0 = {A0.x, A0.y}, Av1 = {A0.z, A0.w};
    vfloat2 Av2 = {A1.x, A1.y}, Av3 = {A1.z, A1.w};
    vfloat2 Av4 = {A2.x, A2.y}, Av5 = {A2.z, A2.w};
    vfloat2 Av6 = {A3.x, A3.y}, Av7 = {A3.z, A3.w};

    // ---- per-row partial dots over the lane's 16 elems ----
    float s[8];
    #pragma unroll
    for (int p = 0; p < 8; ++p) {
        vfloat2 f0 = __builtin_amdgcn_cvt_pk_f32_fp8(q[p].x, false);
        vfloat2 f1 = __builtin_amdgcn_cvt_pk_f32_fp8(q[p].x, true);
        vfloat2 f2 = __builtin_amdgcn_cvt_pk_f32_fp8(q[p].y, false);
        vfloat2 f3 = __builtin_amdgcn_cvt_pk_f32_fp8(q[p].y, true);
        vfloat2 f4 = __builtin_amdgcn_cvt_pk_f32_fp8(q[p].z, false);
        vfloat2 f5 = __builtin_amdgcn_cvt_pk_f32_fp8(q[p].z, true);
        vfloat2 f6 = __builtin_amdgcn_cvt_pk_f32_fp8(q[p].w, false);
        vfloat2 f7 = __builtin_amdgcn_cvt_pk_f32_fp8(q[p].w, true);
        vfloat2 acc = f0 * Av0;       // v_pk_fma_f32 chain
        acc += f1 * Av1;
        acc += f2 * Av2;
        acc += f3 * Av3;
        acc += f4 * Av4;
        acc += f5 * Av5;
        acc += f6 * Av6;
        acc += f7 * Av7;
        s[p] = acc.x + acc.y;
    }

    // ---- 3-round butterfly (R12-validated): lane (g,c) ends with the full
    // dot of row g*8+c (= its own lane id), 64 distinct rows.
    const bool h4 = (c & 4) != 0;
    float t0 = (h4 ? s[4] : s[0]) + __shfl_xor(h4 ? s[0] : s[4], 4, 64);
    float t1 = (h4 ? s[5] : s[1]) + __shfl_xor(h4 ? s[1] : s[5], 4, 64);
    float t2 = (h4 ? s[6] : s[2]) + __shfl_xor(h4 ? s[2] : s[6], 4, 64);
    float t3 = (h4 ? s[7] : s[3]) + __shfl_xor(h4 ? s[3] : s[7], 4, 64);
    const bool h2 = (c & 2) != 0;
    float u0 = (h2 ? t2 : t0) + __shfl_xor(h2 ? t0 : t2, 2, 64);
    float u1 = (h2 ? t3 : t1) + __shfl_xor(h2 ? t1 : t3, 2, 64);
    const bool h1 = (c & 1) != 0;
    float inner = (h1 ? u1 : u0) + __shfl_xor(h1 ? u0 : u1, 1, 64);

    inner -= app;                // inner[lane] = a.(n_lane - p), exact a.p

    // ---- stable logaddexp(0, logsumexp) over the 64 negatives ----
    float m  = wave_reduce_max(inner);
    float se = wave_reduce_sum(__expf(inner - m));
    float lse = m + __logf(se);
    float per = (lse > 0.f) ? lse + log1pf(__expf(-lse)) : log1pf(__expf(lse));

    if (lane == 0) red[wave] = per * (1.0f / (float)A_SZ);    // pre-scaled
    __syncthreads();
    if (threadIdx.x == 0)
        partial[CONV_BLK + blockIdx.x] = red[0] + red[1] + red[2] + red[3];
}

// ---- fp32 fallback (R6-validated, absmax 0.0; grid F32BLK=4096) ----
__global__ __launch_bounds__(256) void f32_kernel(const float* __restrict__ embed,
                                                  const int* __restrict__ anc_ind,
                                                  const int* __restrict__ pos_ind,
                                                  const int* __restrict__ neg_ind,
                                                  float* __restrict__ partial) {
    __shared__ float mw[4], sew[4], nw[4];
    const int wave = threadIdx.x >> 6;
    const int lane = threadIdx.x & 63;
    const int i    = blockIdx.x * 2 + (wave >> 1);
    const int w    = wave & 1;
    const int g    = lane >> 3;
    const int c    = lane & 7;

    const int4 nb = *(const int4*)(neg_ind + (size_t)i * K_SZ + w * 32 + g * 4);
    const int ai = anc_ind[i];
    const int pi = pos_ind[i];
    const float4* a4 = (const float4*)(embed + (size_t)ai * D_DIM);
    float4 A0 = a4[c], A1 = a4[c + 8], A2 = a4[c + 16], A3 = a4[c + 24];

    const float4* r0 = (const float4*)(embed + (size_t)nb.x * D_DIM);
    const float4* r1 = (const float4*)(embed + (size_t)nb.y * D_DIM);
    const float4* r2 = (const float4*)(embed + (size_t)nb.z * D_DIM);
    const float4* r3 = (const float4*)(embed + (size_t)nb.w * D_DIM);
    float4 q00 = r0[c], q01 = r0[c + 8], q02 = r0[c + 16], q03 = r0[c + 24];
    float4 q10 = r1[c], q11 = r1[c + 8], q12 = r1[c + 16], q13 = r1[c + 24];
    float4 q20 = r2[c], q21 = r2[c + 8], q22 = r2[c + 16], q23 = r2[c + 24];
    float4 q30 = r3[c], q31 = r3[c + 8], q32 = r3[c + 16], q33 = r3[c + 24];

    const float4* p4 = (const float4*)(embed + (size_t)pi * D_DIM);
    float4 P0 = p4[c], P1 = p4[c + 8], P2 = p4[c + 16], P3 = p4[c + 24];
    const int nrow_id = blockIdx.x * 4 + wave;
    float2 nv = ((const float2*)(embed + (size_t)nrow_id * D_DIM))[lane];

    float app = dot4(A0, P0) + dot4(A1, P1) + dot4(A2, P2) + dot4(A3, P3);
    app += __shfl_xor(app, 1, 64);
    app += __shfl_xor(app, 2, 64);
    app += __shfl_xor(app, 4, 64);

    float sq = wave_reduce_sum(nv.x * nv.x + nv.y * nv.y);

    float s0 = dot4(A0, q00) + dot4(A1, q01) + dot4(A2, q02) + dot4(A3, q03);
    float s1 = dot4(A0, q10) + dot4(A1, q11) + dot4(A2, q12) + dot4(A3, q13);
    float s2 = dot4(A0, q20) + dot4(A1, q21) + dot4(A2, q22) + dot4(A3, q23);
    float s3 = dot4(A0, q30) + dot4(A1, q31) + dot4(A2, q32) + dot4(A3, q33);

    const bool h4 = (c & 4) != 0;
    float t0 = (h4 ? s2 : s0) + __shfl_xor(h4 ? s0 : s2, 4, 64);
    float t1 = (h4 ? s3 : s1) + __shfl_xor(h4 ? s1 : s3, 4, 64);
    const bool h2 = (c & 2) != 0;
    float u = (h2 ? t1 : t0) + __shfl_xor(h2 ? t0 : t1, 2, 64);
    u += __shfl_xor(u, 1, 64);
    float inner = u - app;

    float m  = wave_reduce_max(inner);
    float se = 0.5f * wave_reduce_sum(__expf(inner - m));

    if (lane == 0) { mw[wave] = m; sew[wave] = se; nw[wave] = sqrtf(sq); }
    __syncthreads();
    if (threadIdx.x == 0) {
        float total = 0.f;
        #pragma unroll
        for (int a = 0; a < 2; ++a) {
            float m0 = mw[2 * a], m1 = mw[2 * a + 1];
            float mm = fmaxf(m0, m1);
            float ss = sew[2 * a] * __expf(m0 - mm) + sew[2 * a + 1] * __expf(m1 - mm);
            float lse = mm + __logf(ss);
            float per = (lse > 0.f) ? lse + log1pf(__expf(-lse)) : log1pf(__expf(lse));
            total += per * (1.0f / (float)A_SZ);
        }
        total += (nw[0] + nw[1] + nw[2] + nw[3]) * (L2_REG_F / (float)B_SZ);
        partial[blockIdx.x] = total;
    }
}

__global__ __launch_bounds__(256) void finalize_kernel(const float* __restrict__ partial,
                                                       int n, float* __restrict__ out) {
    __shared__ float red[4];
    const int wave = threadIdx.x >> 6;
    const int lane = threadIdx.x & 63;
    float v = 0.f;
    for (int j = threadIdx.x; j < n; j += 256) v += partial[j];
    v = wave_reduce_sum(v);
    if (lane == 0) red[wave] = v;
    __syncthreads();
    if (threadIdx.x == 0)
        out[0] = red[0] + red[1] + red[2] + red[3];
}

extern "C" void kernel_launch(void* const* d_in, const int* in_sizes, int n_in,
                              void* d_out, int out_size, void* d_ws, size_t ws_size,
                              hipStream_t stream) {
    const float* embed = (const float*)d_in[0];
    const int*   anc   = (const int*)d_in[1];
    const int*   pos   = (const int*)d_in[2];
    const int*   neg   = (const int*)d_in[3];
    float* out = (float*)d_out;

    const size_t tab_bytes = (size_t)B_SZ * D_DIM;   // 2 MB fp8
    const size_t need = tab_bytes + NPART * sizeof(float);

    if (ws_size >= need) {
        unsigned short* tab = (unsigned short*)d_ws;
        float* partial = (float*)((char*)d_ws + tab_bytes);  // [conv | fused]
        convert_kernel<<<CONV_BLK, 256, 0, stream>>>(embed, tab, partial);
        // DECOMPOSITION PROBE: fused x4 (idempotent). fused_dur=(tot-81.3)/3
        fused_kernel<<<NBLK, 256, 0, stream>>>(embed, tab, anc, pos, neg, partial);
        fused_kernel<<<NBLK, 256, 0, stream>>>(embed, tab, anc, pos, neg, partial);
        fused_kernel<<<NBLK, 256, 0, stream>>>(embed, tab, anc, pos, neg, partial);
        fused_kernel<<<NBLK, 256, 0, stream>>>(embed, tab, anc, pos, neg, partial);
        finalize_kernel<<<1, 256, 0, stream>>>(partial, NPART, out);
    } else {
        float* partial = (float*)d_ws;
        f32_kernel<<<F32BLK, 256, 0, stream>>>(embed, anc, pos, neg, partial);
        finalize_kernel<<<1, 256, 0, stream>>>(partial, F32BLK, out);
    }
}

// Round 22
// 80.013 us; speedup vs baseline: 1.3700x; 1.3700x over previous
//
#include <hip/hip_runtime.h>
#include <math.h>

#define B_SZ 16384
#define D_DIM 128
#define A_SZ 8192
#define K_SZ 64
#define L2_REG_F 0.25f
#define CONV_BLK 2048  // convert blocks: 4 waves/block, 2 rows/wave in parallel
#define NBLK 2048      // fused blocks: 4 waves/block, 1 wave per anchor
#define F32BLK 4096    // fp32 fallback blocks (R6-validated geometry)
#define NPART (CONV_BLK + NBLK)

typedef float vfloat2 __attribute__((ext_vector_type(2)));

__device__ __forceinline__ float wave_reduce_sum(float v) {
    #pragma unroll
    for (int off = 32; off > 0; off >>= 1)
        v += __shfl_xor(v, off, 64);
    return v;
}

__device__ __forceinline__ float wave_reduce_max(float v) {
    #pragma unroll
    for (int off = 32; off > 0; off >>= 1)
        v = fmaxf(v, __shfl_xor(v, off, 64));
    return v;
}

__device__ __forceinline__ float dot4(float4 a, float4 b) {
    return a.x * b.x + a.y * b.y + a.z * b.z + a.w * b.w;
}

// Pre-pass: fp32 -> fp8 e4m3 table + exact-fp32 L2-norm sum.
// SINGLE CHANGE vs R19 (math HW-validated in R15, absmax 0.0): float4 loads
// (16B/lane, G13) and both rows processed in PARALLEL (half-wave per row) ->
// serial chain halved vs the float2 2-iteration R12 form. Plain partial
// store (R15: atomic fan-in costs ~10ns/op serialized -- never again).
__global__ __launch_bounds__(256) void convert_kernel(const float* __restrict__ embed,
                                                      unsigned* __restrict__ tab,
                                                      float* __restrict__ partial) {
    __shared__ float red[4];
    const int wave = threadIdx.x >> 6;
    const int lane = threadIdx.x & 63;
    const int gw   = blockIdx.x * 4 + wave;          // 0..8191
    const int half = lane >> 5;                      // row select within wave
    const int hl   = lane & 31;                      // float4 index in row
    const int row  = gw * 2 + half;                  // 0..16383

    float4 v = ((const float4*)(embed + (size_t)row * D_DIM))[hl];

    // exact fp32 norm: within-half reduce (offsets <32 stay in the half)
    float sq = v.x * v.x + v.y * v.y + v.z * v.z + v.w * v.w;
    #pragma unroll
    for (int off = 16; off > 0; off >>= 1)
        sq += __shfl_xor(sq, off, 64);
    float nrm = sqrtf(sq);
    nrm += __shfl_xor(nrm, 32, 64);                  // sum of both rows' norms

    // HW RNE fp32->fp8 e4m3 (OCP): 4 elems -> 1 dword, byte k = elem k
    // (same linear layout as R12's ushort form; HW-validated R15)
    unsigned w01  = (unsigned)__builtin_amdgcn_cvt_pk_fp8_f32(v.x, v.y, 0, false);
    unsigned word = (unsigned)__builtin_amdgcn_cvt_pk_fp8_f32(v.z, v.w, (int)w01, true);
    __builtin_nontemporal_store(word, &tab[(size_t)row * 32 + hl]);

    if (lane == 0) red[wave] = nrm * (L2_REG_F / (float)B_SZ);  // pre-scaled
    __syncthreads();
    if (threadIdx.x == 0)
        partial[blockIdx.x] = red[0] + red[1] + red[2] + red[3];
}

// Main (R12-validated, absmax 0.0; R20 probe: ~9.4us marginal, near the
// MSHR-latency floor of 2048 lines/CU x ~400cy). 8-lane group g owns rows
// g*8+p; lane (g,c) reads 16B fp8 chunk c -> each gather = 8 rows x one
// FULL 128B line (1 line/row). 3-round butterfly -> lane-local inner;
// wave LSE; plain per-block partial store; finalize sums NPART.
__global__ __launch_bounds__(256) void fused_kernel(const float* __restrict__ embed,
                                                    const unsigned short* __restrict__ tab,
                                                    const int* __restrict__ anc_ind,
                                                    const int* __restrict__ pos_ind,
                                                    const int* __restrict__ neg_ind,
                                                    float* __restrict__ partial) {
    __shared__ float red[4];
    const int wave = threadIdx.x >> 6;
    const int lane = threadIdx.x & 63;
    const int i    = blockIdx.x * 4 + wave;          // anchor id 0..8191
    const int g    = lane >> 3;                      // group: rows g*8..g*8+7
    const int c    = lane & 7;                       // 16B chunk in the row

    // ---- this group's 8 row ids (contiguous, no lane shuffle needed) ----
    const int4* nbp = (const int4*)(neg_ind + (size_t)i * K_SZ + g * 8);
    int4 nlo = nbp[0], nhi = nbp[1];

    // ---- a/p chunks: lane covers elems c*16..c*16+15 (4 float4s) ----
    const int ai = anc_ind[i];                       // wave-uniform
    const int pi = pos_ind[i];
    const float4* a4 = (const float4*)(embed + (size_t)ai * D_DIM);
    const float4* p4 = (const float4*)(embed + (size_t)pi * D_DIM);
    float4 A0 = a4[c * 4 + 0], A1 = a4[c * 4 + 1];
    float4 A2 = a4[c * 4 + 2], A3 = a4[c * 4 + 3];
    float4 P0 = p4[c * 4 + 0], P1 = p4[c * 4 + 1];
    float4 P2 = p4[c * 4 + 2], P3 = p4[c * 4 + 3];

    // ---- 8 gathers: one full 128B fp8 line per row, all in flight ----
    int nidx[8] = {nlo.x, nlo.y, nlo.z, nlo.w, nhi.x, nhi.y, nhi.z, nhi.w};
    uint4 q[8];
    #pragma unroll
    for (int p = 0; p < 8; ++p)
        q[p] = ((const uint4*)(tab + (size_t)nidx[p] * 64))[c];

    // ---- a.p (exact): lane's 16-elem partial, 3-shfl group reduce ----
    float app = dot4(A0, P0) + dot4(A1, P1) + dot4(A2, P2) + dot4(A3, P3);
    app += __shfl_xor(app, 1, 64);
    app += __shfl_xor(app, 2, 64);
    app += __shfl_xor(app, 4, 64);

    // packed-fp32 A pairs for the fp8 dot chain
    vfloat2 Av0 = {A0.x, A0.y}, Av1 = {A0.z, A0.w};
    vfloat2 Av2 = {A1.x, A1.y}, Av3 = {A1.z, A1.w};
    vfloat2 Av4 = {A2.x, A2.y}, Av5 = {A2.z, A2.w};
    vfloat2 Av6 = {A3.x, A3.y}, Av7 = {A3.z, A3.w};

    // ---- per-row partial dots over the lane's 16 elems ----
    float s[8];
    #pragma unroll
    for (int p = 0; p < 8; ++p) {
        vfloat2 f0 = __builtin_amdgcn_cvt_pk_f32_fp8(q[p].x, false);
        vfloat2 f1 = __builtin_amdgcn_cvt_pk_f32_fp8(q[p].x, true);
        vfloat2 f2 = __builtin_amdgcn_cvt_pk_f32_fp8(q[p].y, false);
        vfloat2 f3 = __builtin_amdgcn_cvt_pk_f32_fp8(q[p].y, true);
        vfloat2 f4 = __builtin_amdgcn_cvt_pk_f32_fp8(q[p].z, false);
        vfloat2 f5 = __builtin_amdgcn_cvt_pk_f32_fp8(q[p].z, true);
        vfloat2 f6 = __builtin_amdgcn_cvt_pk_f32_fp8(q[p].w, false);
        vfloat2 f7 = __builtin_amdgcn_cvt_pk_f32_fp8(q[p].w, true);
        vfloat2 acc = f0 * Av0;       // v_pk_fma_f32 chain
        acc += f1 * Av1;
        acc += f2 * Av2;
        acc += f3 * Av3;
        acc += f4 * Av4;
        acc += f5 * Av5;
        acc += f6 * Av6;
        acc += f7 * Av7;
        s[p] = acc.x + acc.y;
    }

    // ---- 3-round butterfly (R12-validated): lane (g,c) ends with the full
    // dot of row g*8+c (= its own lane id), 64 distinct rows.
    const bool h4 = (c & 4) != 0;
    float t0 = (h4 ? s[4] : s[0]) + __shfl_xor(h4 ? s[0] : s[4], 4, 64);
    float t1 = (h4 ? s[5] : s[1]) + __shfl_xor(h4 ? s[1] : s[5], 4, 64);
    float t2 = (h4 ? s[6] : s[2]) + __shfl_xor(h4 ? s[2] : s[6], 4, 64);
    float t3 = (h4 ? s[7] : s[3]) + __shfl_xor(h4 ? s[3] : s[7], 4, 64);
    const bool h2 = (c & 2) != 0;
    float u0 = (h2 ? t2 : t0) + __shfl_xor(h2 ? t0 : t2, 2, 64);
    float u1 = (h2 ? t3 : t1) + __shfl_xor(h2 ? t1 : t3, 2, 64);
    const bool h1 = (c & 1) != 0;
    float inner = (h1 ? u1 : u0) + __shfl_xor(h1 ? u0 : u1, 1, 64);

    inner -= app;                // inner[lane] = a.(n_lane - p), exact a.p

    // ---- stable logaddexp(0, logsumexp) over the 64 negatives ----
    float m  = wave_reduce_max(inner);
    float se = wave_reduce_sum(__expf(inner - m));
    float lse = m + __logf(se);
    float per = (lse > 0.f) ? lse + log1pf(__expf(-lse)) : log1pf(__expf(lse));

    if (lane == 0) red[wave] = per * (1.0f / (float)A_SZ);    // pre-scaled
    __syncthreads();
    if (threadIdx.x == 0)
        partial[CONV_BLK + blockIdx.x] = red[0] + red[1] + red[2] + red[3];
}

// ---- fp32 fallback (R6-validated, absmax 0.0; grid F32BLK=4096) ----
__global__ __launch_bounds__(256) void f32_kernel(const float* __restrict__ embed,
                                                  const int* __restrict__ anc_ind,
                                                  const int* __restrict__ pos_ind,
                                                  const int* __restrict__ neg_ind,
                                                  float* __restrict__ partial) {
    __shared__ float mw[4], sew[4], nw[4];
    const int wave = threadIdx.x >> 6;
    const int lane = threadIdx.x & 63;
    const int i    = blockIdx.x * 2 + (wave >> 1);
    const int w    = wave & 1;
    const int g    = lane >> 3;
    const int c    = lane & 7;

    const int4 nb = *(const int4*)(neg_ind + (size_t)i * K_SZ + w * 32 + g * 4);
    const int ai = anc_ind[i];
    const int pi = pos_ind[i];
    const float4* a4 = (const float4*)(embed + (size_t)ai * D_DIM);
    float4 A0 = a4[c], A1 = a4[c + 8], A2 = a4[c + 16], A3 = a4[c + 24];

    const float4* r0 = (const float4*)(embed + (size_t)nb.x * D_DIM);
    const float4* r1 = (const float4*)(embed + (size_t)nb.y * D_DIM);
    const float4* r2 = (const float4*)(embed + (size_t)nb.z * D_DIM);
    const float4* r3 = (const float4*)(embed + (size_t)nb.w * D_DIM);
    float4 q00 = r0[c], q01 = r0[c + 8], q02 = r0[c + 16], q03 = r0[c + 24];
    float4 q10 = r1[c], q11 = r1[c + 8], q12 = r1[c + 16], q13 = r1[c + 24];
    float4 q20 = r2[c], q21 = r2[c + 8], q22 = r2[c + 16], q23 = r2[c + 24];
    float4 q30 = r3[c], q31 = r3[c + 8], q32 = r3[c + 16], q33 = r3[c + 24];

    const float4* p4 = (const float4*)(embed + (size_t)pi * D_DIM);
    float4 P0 = p4[c], P1 = p4[c + 8], P2 = p4[c + 16], P3 = p4[c + 24];
    const int nrow_id = blockIdx.x * 4 + wave;
    float2 nv = ((const float2*)(embed + (size_t)nrow_id * D_DIM))[lane];

    float app = dot4(A0, P0) + dot4(A1, P1) + dot4(A2, P2) + dot4(A3, P3);
    app += __shfl_xor(app, 1, 64);
    app += __shfl_xor(app, 2, 64);
    app += __shfl_xor(app, 4, 64);

    float sq = wave_reduce_sum(nv.x * nv.x + nv.y * nv.y);

    float s0 = dot4(A0, q00) + dot4(A1, q01) + dot4(A2, q02) + dot4(A3, q03);
    float s1 = dot4(A0, q10) + dot4(A1, q11) + dot4(A2, q12) + dot4(A3, q13);
    float s2 = dot4(A0, q20) + dot4(A1, q21) + dot4(A2, q22) + dot4(A3, q23);
    float s3 = dot4(A0, q30) + dot4(A1, q31) + dot4(A2, q32) + dot4(A3, q33);

    const bool h4 = (c & 4) != 0;
    float t0 = (h4 ? s2 : s0) + __shfl_xor(h4 ? s0 : s2, 4, 64);
    float t1 = (h4 ? s3 : s1) + __shfl_xor(h4 ? s1 : s3, 4, 64);
    const bool h2 = (c & 2) != 0;
    float u = (h2 ? t1 : t0) + __shfl_xor(h2 ? t0 : t1, 2, 64);
    u += __shfl_xor(u, 1, 64);
    float inner = u - app;

    float m  = wave_reduce_max(inner);
    float se = 0.5f * wave_reduce_sum(__expf(inner - m));

    if (lane == 0) { mw[wave] = m; sew[wave] = se; nw[wave] = sqrtf(sq); }
    __syncthreads();
    if (threadIdx.x == 0) {
        float total = 0.f;
        #pragma unroll
        for (int a = 0; a < 2; ++a) {
            float m0 = mw[2 * a], m1 = mw[2 * a + 1];
            float mm = fmaxf(m0, m1);
            float ss = sew[2 * a] * __expf(m0 - mm) + sew[2 * a + 1] * __expf(m1 - mm);
            float lse = mm + __logf(ss);
            float per = (lse > 0.f) ? lse + log1pf(__expf(-lse)) : log1pf(__expf(lse));
            total += per * (1.0f / (float)A_SZ);
        }
        total += (nw[0] + nw[1] + nw[2] + nw[3]) * (L2_REG_F / (float)B_SZ);
        partial[blockIdx.x] = total;
    }
}

__global__ __launch_bounds__(256) void finalize_kernel(const float* __restrict__ partial,
                                                       int n, float* __restrict__ out) {
    __shared__ float red[4];
    const int wave = threadIdx.x >> 6;
    const int lane = threadIdx.x & 63;
    float v = 0.f;
    for (int j = threadIdx.x; j < n; j += 256) v += partial[j];
    v = wave_reduce_sum(v);
    if (lane == 0) red[wave] = v;
    __syncthreads();
    if (threadIdx.x == 0)
        out[0] = red[0] + red[1] + red[2] + red[3];
}

extern "C" void kernel_launch(void* const* d_in, const int* in_sizes, int n_in,
                              void* d_out, int out_size, void* d_ws, size_t ws_size,
                              hipStream_t stream) {
    const float* embed = (const float*)d_in[0];
    const int*   anc   = (const int*)d_in[1];
    const int*   pos   = (const int*)d_in[2];
    const int*   neg   = (const int*)d_in[3];
    float* out = (float*)d_out;

    const size_t tab_bytes = (size_t)B_SZ * D_DIM;   // 2 MB fp8
    const size_t need = tab_bytes + NPART * sizeof(float);

    if (ws_size >= need) {
        unsigned* tab = (unsigned*)d_ws;
        float* partial = (float*)((char*)d_ws + tab_bytes);  // [conv | fused]
        convert_kernel<<<CONV_BLK, 256, 0, stream>>>(embed, tab, partial);
        fused_kernel<<<NBLK, 256, 0, stream>>>(embed, (const unsigned short*)d_ws,
                                               anc, pos, neg, partial);
        finalize_kernel<<<1, 256, 0, stream>>>(partial, NPART, out);
    } else {
        float* partial = (float*)d_ws;
        f32_kernel<<<F32BLK, 256, 0, stream>>>(embed, anc, pos, neg, partial);
        finalize_kernel<<<1, 256, 0, stream>>>(partial, F32BLK, out);
    }
}